// Round 1
// baseline (6611.357 us; speedup 1.0000x reference)
//
#include <hip/hip_runtime.h>

#define N_NODESC 20000
#define N_EDGESC 640000

typedef _Float16 f16;
typedef __attribute__((ext_vector_type(4))) _Float16 f16x4;
typedef __attribute__((ext_vector_type(8))) _Float16 f16x8;
typedef __attribute__((ext_vector_type(4))) float f32x4;

__device__ __forceinline__ f32x4 mfma16(f16x8 a, f16x8 b, f32x4 c){
  return __builtin_amdgcn_mfma_f32_16x16x32_f16(a, b, c, 0, 0, 0);
}
__device__ __forceinline__ float sigm(float x){ return 1.f/(1.f+__expf(-x)); }
__device__ __forceinline__ float tanh_(float x){
  x = fminf(fmaxf(x, -15.f), 15.f);
  float e = __expf(-2.f*x);
  return (1.f - e)/(1.f + e);
}

// ---------------- CSR construction ----------------
__global__ __launch_bounds__(256) void k_hist(const int* __restrict__ dst, int* __restrict__ cnt){
  int e = blockIdx.x*256 + threadIdx.x;
  if(e < N_EDGESC) atomicAdd(&cnt[dst[e]], 1);
}

__global__ __launch_bounds__(1024) void k_scan(const int* __restrict__ cnt, int* __restrict__ row_ptr,
    float* __restrict__ deg_inv, float* __restrict__ deg_is){
  __shared__ int wsum[16];
  int t = threadIdx.x;
  int base = t*20;
  int loc[20]; int s = 0;
  #pragma unroll
  for(int i=0;i<20;i++){ int idx=base+i; int v = (idx<N_NODESC)? cnt[idx] : 0; loc[i]=s; s+=v; }
  int lane = t&63, wv = t>>6;
  int incl = s;
  #pragma unroll
  for(int off=1; off<64; off<<=1){ int u = __shfl_up(incl, off); if(lane>=off) incl += u; }
  if(lane==63) wsum[wv]=incl;
  __syncthreads();
  int woff=0;
  for(int i=0;i<wv;i++) woff += wsum[i];
  int excl = woff + incl - s;
  #pragma unroll
  for(int i=0;i<20;i++){
    int idx=base+i;
    if(idx<N_NODESC){
      row_ptr[idx] = excl + loc[i];
      float d = (float)(cnt[idx]+1);
      deg_inv[idx] = 1.f/d;
      deg_is[idx]  = rsqrtf(d);
    }
  }
  if(t==1023) row_ptr[N_NODESC] = woff + incl;
}

__global__ __launch_bounds__(256) void k_fill(const int* __restrict__ src, const int* __restrict__ dst,
    const int* __restrict__ row_ptr, int* __restrict__ cursor, const float* __restrict__ deg_is,
    int* __restrict__ colv, float* __restrict__ normv){
  int e = blockIdx.x*256 + threadIdx.x;
  if(e >= N_EDGESC) return;
  int d = dst[e], s = src[e];
  int p = atomicAdd(&cursor[d], 1);
  int idx = row_ptr[d] + p;
  colv[idx] = s;
  normv[idx] = deg_is[s]*deg_is[d];
}

// ---------------- weight packing (f16, MFMA B-fragment order) ----------------
// Bp[((kb*NO + c)*4 + g)*8 + i] = B[k = kb*32 + g*8 + i][c]
__global__ __launch_bounds__(256) void k_pack(const float* __restrict__ w, f16* __restrict__ dstp,
    int K, int NO, int trans){
  int t = blockIdx.x*256 + threadIdx.x;
  if(t >= K*NO) return;
  int i = t&7, g = (t>>3)&3, rest = t>>5;
  int c = rest % NO, kb = rest / NO;
  int k = kb*32 + g*8 + i;
  float v = trans ? w[(size_t)c*K + k] : w[(size_t)k*NO + c];
  dstp[t] = (f16)v;
}

// ---------------- aggregation: out = deg_inv*x + sum_e norm*x[src] ----------------
__global__ __launch_bounds__(256) void k_agg256(const float* __restrict__ x,
    const int* __restrict__ row_ptr, const int* __restrict__ colv,
    const float* __restrict__ normv, const float* __restrict__ deg_inv,
    float* __restrict__ out){
  int n = (blockIdx.x*256 + threadIdx.x)>>6;
  int lane = threadIdx.x&63;
  if(n >= N_NODESC) return;
  const f32x4* xv = (const f32x4*)x;
  f32x4 acc = xv[(size_t)n*64 + lane] * deg_inv[n];
  int e0 = row_ptr[n], e1 = row_ptr[n+1];
  int e = e0;
  for(; e+4<=e1; e+=4){
    int s0=colv[e],s1=colv[e+1],s2=colv[e+2],s3=colv[e+3];
    float w0=normv[e],w1=normv[e+1],w2=normv[e+2],w3=normv[e+3];
    f32x4 v0=xv[(size_t)s0*64+lane], v1=xv[(size_t)s1*64+lane];
    f32x4 v2=xv[(size_t)s2*64+lane], v3=xv[(size_t)s3*64+lane];
    acc += v0*w0; acc += v1*w1; acc += v2*w2; acc += v3*w3;
  }
  for(; e<e1; e++) acc += xv[(size_t)colv[e]*64+lane]*normv[e];
  ((f32x4*)out)[(size_t)n*64+lane] = acc;
}

__global__ __launch_bounds__(256) void k_agg64(const float* __restrict__ x,
    const int* __restrict__ row_ptr, const int* __restrict__ colv,
    const float* __restrict__ normv, const float* __restrict__ deg_inv,
    float* __restrict__ out){
  int n = (blockIdx.x*256 + threadIdx.x)>>6;
  int c = threadIdx.x&63;
  if(n >= N_NODESC) return;
  float acc = deg_inv[n]*x[(size_t)n*64 + c];
  int e0 = row_ptr[n], e1 = row_ptr[n+1];
  int e = e0;
  for(; e+4<=e1; e+=4){
    int s0=colv[e],s1=colv[e+1],s2=colv[e+2],s3=colv[e+3];
    float w0=normv[e],w1=normv[e+1],w2=normv[e+2],w3=normv[e+3];
    float v0=x[(size_t)s0*64+c], v1=x[(size_t)s1*64+c];
    float v2=x[(size_t)s2*64+c], v3=x[(size_t)s3*64+c];
    acc += w0*v0 + w1*v1 + w2*v2 + w3*v3;
  }
  for(; e<e1; e++) acc += normv[e]*x[(size_t)colv[e]*64+c];
  out[(size_t)n*64+c] = acc;
}

// ---------------- generic f16x2-split GEMM: C = act(A@B + bias) ----------------
// A [20000,K] f32, Bp packed f16 [K,NO], C [20000,NO] f32. BM=64, 4 waves, wave = 64r x (NO/4)c.
template<int K, int NO, bool RELU>
__global__ __launch_bounds__(256) void k_gemm(const float* __restrict__ A,
    const f16* __restrict__ Bp, const float* __restrict__ bias, float* __restrict__ C){
  constexpr int KC = (K > 128) ? 128 : K;
  constexpr int CT = NO/64;           // 16-col tiles per wave
  __shared__ f16 a_hi[64*KC];
  __shared__ f16 a_lo[64*KC];
  const int tid = threadIdx.x, lane = tid&63, w = tid>>6;
  const int m0 = blockIdx.x*64;
  const int c0 = w*(NO/4);
  f32x4 acc[4][CT];
  #pragma unroll
  for(int rt=0;rt<4;rt++)
    #pragma unroll
    for(int ct=0;ct<CT;ct++) acc[rt][ct] = (f32x4){0.f,0.f,0.f,0.f};

  for(int ch=0; ch<K/KC; ch++){
    __syncthreads();
    #pragma unroll
    for(int it=0; it<(64*KC)/1024; it++){
      int f = (it*256 + tid)*4;
      int row = f/KC, k0 = f%KC;
      f32x4 v = {0.f,0.f,0.f,0.f};
      int gr = m0+row;
      if(gr < N_NODESC) v = *(const f32x4*)(A + (size_t)gr*K + ch*KC + k0);
      f16x4 vh, vl;
      #pragma unroll
      for(int j=0;j<4;j++){ f16 hh=(f16)v[j]; vh[j]=hh; vl[j]=(f16)(v[j]-(float)hh); }
      int byte = (row*KC + k0)*2 ^ ((row&7)<<4);
      *(f16x4*)((char*)a_hi + byte) = vh;
      *(f16x4*)((char*)a_lo + byte) = vl;
    }
    __syncthreads();
    for(int kl=0; kl<KC; kl+=32){
      int kb = (ch*KC + kl)>>5;
      f16x8 bf[CT];
      #pragma unroll
      for(int ct=0;ct<CT;ct++){
        int c = c0 + ct*16 + (lane&15);
        bf[ct] = *(const f16x8*)(Bp + (((size_t)kb*NO + c)*4 + (lane>>4))*8);
      }
      #pragma unroll
      for(int rt=0;rt<4;rt++){
        int row = rt*16 + (lane&15);
        int byte = (row*KC + kl + (lane>>4)*8)*2 ^ ((row&7)<<4);
        f16x8 ah = *(const f16x8*)((char*)a_hi + byte);
        f16x8 al = *(const f16x8*)((char*)a_lo + byte);
        #pragma unroll
        for(int ct=0;ct<CT;ct++){
          acc[rt][ct] = mfma16(ah, bf[ct], acc[rt][ct]);
          acc[rt][ct] = mfma16(al, bf[ct], acc[rt][ct]);
        }
      }
    }
  }
  #pragma unroll
  for(int rt=0;rt<4;rt++){
    #pragma unroll
    for(int ct=0;ct<CT;ct++){
      int c = c0 + ct*16 + (lane&15);
      float bv = bias[c];
      #pragma unroll
      for(int j=0;j<4;j++){
        int r = m0 + rt*16 + (lane>>4)*4 + j;
        if(r < N_NODESC){
          float v = acc[rt][ct][j] + bv;
          if(RELU) v = fmaxf(v, 0.f);
          C[(size_t)r*NO + c] = v;
        }
      }
    }
  }
}

// ---------------- fused GRU cell: Hnew = GRU(X, Hold) ----------------
// grid (4 colblocks, 313 rowblocks); block 256 = 4 waves; wave = 64 rows x 16 cols; 6 gate mats.
__global__ __launch_bounds__(256) void k_gru(const float* __restrict__ X,
    const float* __restrict__ Hold, float* __restrict__ Hnew,
    const f16* __restrict__ Wi, const f16* __restrict__ Wh,
    const float* __restrict__ bih, const float* __restrict__ bhh){
  __shared__ f16 sxh[64*32], sxl[64*32], shh_[64*32], shl[64*32];
  const int tid = threadIdx.x, lane = tid&63, cw = tid>>6;
  const int m0 = blockIdx.y*64;
  const int cc = blockIdx.x*64 + cw*16 + (lane&15);   // output channel [0,256)
  f32x4 acc[6][4];
  #pragma unroll
  for(int m=0;m<6;m++)
    #pragma unroll
    for(int rt=0;rt<4;rt++) acc[m][rt] = (f32x4){0.f,0.f,0.f,0.f};

  for(int kb=0; kb<8; kb++){
    __syncthreads();
    #pragma unroll
    for(int it=0; it<2; it++){
      int f = (it*256 + tid)*4;        // [64][32] chunk
      int row = f>>5, k0 = f&31;
      int gr = m0+row;
      f32x4 vx={0.f,0.f,0.f,0.f}, vh={0.f,0.f,0.f,0.f};
      if(gr < N_NODESC){
        vx = *(const f32x4*)(X   + (size_t)gr*256 + kb*32 + k0);
        vh = *(const f32x4*)(Hold+ (size_t)gr*256 + kb*32 + k0);
      }
      f16x4 a,b,c,d;
      #pragma unroll
      for(int j=0;j<4;j++){
        f16 t1=(f16)vx[j]; a[j]=t1; b[j]=(f16)(vx[j]-(float)t1);
        f16 t2=(f16)vh[j]; c[j]=t2; d[j]=(f16)(vh[j]-(float)t2);
      }
      int byte = (row*32 + k0)*2 ^ ((row&7)<<4);
      *(f16x4*)((char*)sxh + byte) = a;
      *(f16x4*)((char*)sxl + byte) = b;
      *(f16x4*)((char*)shh_+ byte) = c;
      *(f16x4*)((char*)shl + byte) = d;
    }
    __syncthreads();
    f16x8 bf[6];
    #pragma unroll
    for(int gate=0; gate<3; gate++){
      size_t o = (((size_t)kb*768 + (cc + gate*256))*4 + (lane>>4))*8;
      bf[gate]   = *(const f16x8*)(Wi + o);
      bf[3+gate] = *(const f16x8*)(Wh + o);
    }
    #pragma unroll
    for(int rt=0;rt<4;rt++){
      int row = rt*16 + (lane&15);
      int byte = (row*32 + (lane>>4)*8)*2 ^ ((row&7)<<4);
      f16x8 axh = *(const f16x8*)((char*)sxh + byte);
      f16x8 axl = *(const f16x8*)((char*)sxl + byte);
      f16x8 ahh = *(const f16x8*)((char*)shh_+ byte);
      f16x8 ahl = *(const f16x8*)((char*)shl + byte);
      #pragma unroll
      for(int gate=0;gate<3;gate++){
        acc[gate][rt]   = mfma16(axh, bf[gate],   acc[gate][rt]);
        acc[gate][rt]   = mfma16(axl, bf[gate],   acc[gate][rt]);
        acc[3+gate][rt] = mfma16(ahh, bf[3+gate], acc[3+gate][rt]);
        acc[3+gate][rt] = mfma16(ahl, bf[3+gate], acc[3+gate][rt]);
      }
    }
  }
  float bir=bih[cc], biz=bih[cc+256], bin=bih[cc+512];
  float bhr=bhh[cc], bhz=bhh[cc+256], bhn=bhh[cc+512];
  #pragma unroll
  for(int rt=0;rt<4;rt++){
    #pragma unroll
    for(int j=0;j<4;j++){
      int r = m0 + rt*16 + (lane>>4)*4 + j;
      if(r < N_NODESC){
        float ir=acc[0][rt][j], iz=acc[1][rt][j], in_=acc[2][rt][j];
        float hr=acc[3][rt][j], hz=acc[4][rt][j], hn=acc[5][rt][j];
        float rg = sigm(ir+bir + hr+bhr);
        float zg = sigm(iz+biz + hz+bhz);
        float ng = tanh_(in_+bin + rg*(hn+bhn));
        float ho = Hold[(size_t)r*256 + cc];
        Hnew[(size_t)r*256 + cc] = (1.f-zg)*ng + zg*ho;
      }
    }
  }
}

// ---------------- launcher ----------------
extern "C" void kernel_launch(void* const* d_in, const int* in_sizes, int n_in,
                              void* d_out, int out_size, void* d_ws, size_t ws_size,
                              hipStream_t stream){
  const float* x_seq  = (const float*)d_in[0];
  const int*   srcp   = (const int*)  d_in[1];
  const int*   dstp   = (const int*)  d_in[2];
  const float* gcn1_w = (const float*)d_in[3];
  const float* gcn1_b = (const float*)d_in[4];
  const float* gcn2_w = (const float*)d_in[5];
  const float* gcn2_b = (const float*)d_in[6];
  const float* proj_w = (const float*)d_in[7];
  const float* proj_b = (const float*)d_in[8];
  const float* wih[3] = {(const float*)d_in[9],  (const float*)d_in[13], (const float*)d_in[17]};
  const float* whh[3] = {(const float*)d_in[10], (const float*)d_in[14], (const float*)d_in[18]};
  const float* bih[3] = {(const float*)d_in[11], (const float*)d_in[15], (const float*)d_in[19]};
  const float* bhh[3] = {(const float*)d_in[12], (const float*)d_in[16], (const float*)d_in[20]};
  float* out = (float*)d_out;

  char* p = (char*)d_ws;
  auto alloc = [&](size_t bytes)->char*{ char* r = p; p += (bytes + 255) & ~(size_t)255; return r; };
  int*   deg_cnt = (int*)  alloc((size_t)2*N_NODESC*4);   // [deg_cnt | cursor] contiguous
  int*   cursor  = deg_cnt + N_NODESC;
  int*   row_ptr = (int*)  alloc((size_t)(N_NODESC+1)*4);
  float* deg_inv = (float*)alloc((size_t)N_NODESC*4);
  float* deg_is  = (float*)alloc((size_t)N_NODESC*4);
  int*   colv    = (int*)  alloc((size_t)N_EDGESC*4);
  float* normv   = (float*)alloc((size_t)N_EDGESC*4);
  float* z64     = (float*)alloc((size_t)N_NODESC*64*4);
  float* x1      = (float*)alloc((size_t)N_NODESC*256*4);
  float* xa      = (float*)alloc((size_t)N_NODESC*256*4); // z2 and x2 (in-place safe)
  float* hbuf    = (float*)alloc((size_t)2*3*N_NODESC*256*4); // [slot][gru][N*256]
  f16* pk_gcn1 = (f16*)alloc((size_t)64*256*2);
  f16* pk_gcn2 = (f16*)alloc((size_t)256*256*2);
  f16* pk_proj = (f16*)alloc((size_t)256*64*2);
  f16* pk_wi[3]; f16* pk_wh[3];
  for(int i=0;i<3;i++){ pk_wi[i]=(f16*)alloc((size_t)256*768*2); pk_wh[i]=(f16*)alloc((size_t)256*768*2); }

  hipMemsetAsync(deg_cnt, 0, (size_t)2*N_NODESC*4, stream);
  hipMemsetAsync(hbuf,    0, (size_t)3*N_NODESC*256*4, stream);   // slot 0 = h0

  k_hist<<<2500,256,0,stream>>>(dstp, deg_cnt);
  k_scan<<<1,1024,0,stream>>>(deg_cnt, row_ptr, deg_inv, deg_is);
  k_fill<<<2500,256,0,stream>>>(srcp, dstp, row_ptr, cursor, deg_is, colv, normv);

  k_pack<<<64, 256,0,stream>>>(gcn1_w, pk_gcn1, 64, 256, 0);
  k_pack<<<256,256,0,stream>>>(gcn2_w, pk_gcn2, 256,256, 0);
  k_pack<<<64, 256,0,stream>>>(proj_w, pk_proj, 256, 64, 0);
  for(int i=0;i<3;i++){
    k_pack<<<768,256,0,stream>>>(wih[i], pk_wi[i], 256, 768, 1);
    k_pack<<<768,256,0,stream>>>(whh[i], pk_wh[i], 256, 768, 1);
  }

  auto Hs = [&](int slot, int g)->float*{ return hbuf + ((size_t)slot*3 + g)*N_NODESC*256; };

  for(int s=0; s<18; s++){
    const float* xt;
    if(s < 12)       xt = x_seq + (size_t)s*N_NODESC*64;
    else if(s == 12) xt = x_seq + (size_t)11*N_NODESC*64;
    else             xt = out   + (size_t)(s-13)*N_NODESC*64;
    int cur = s&1, nxt = cur^1;

    k_agg64 <<<5000,256,0,stream>>>(xt, row_ptr, colv, normv, deg_inv, z64);
    k_gemm<64,256,true> <<<313,256,0,stream>>>(z64, pk_gcn1, gcn1_b, x1);
    k_agg256<<<5000,256,0,stream>>>(x1, row_ptr, colv, normv, deg_inv, xa);
    k_gemm<256,256,true><<<313,256,0,stream>>>(xa, pk_gcn2, gcn2_b, xa);

    k_gru<<<dim3(4,313),256,0,stream>>>(xa,         Hs(cur,0), Hs(nxt,0), pk_wi[0], pk_wh[0], bih[0], bhh[0]);
    k_gru<<<dim3(4,313),256,0,stream>>>(Hs(nxt,0),  Hs(cur,1), Hs(nxt,1), pk_wi[1], pk_wh[1], bih[1], bhh[1]);
    k_gru<<<dim3(4,313),256,0,stream>>>(Hs(nxt,1),  Hs(cur,2), Hs(nxt,2), pk_wi[2], pk_wh[2], bih[2], bhh[2]);

    if(s >= 12)
      k_gemm<256,64,false><<<313,256,0,stream>>>(Hs(nxt,2), pk_proj, proj_b, out + (size_t)(s-12)*N_NODESC*64);
  }
}

// Round 2
// 4937.527 us; speedup vs baseline: 1.3390x; 1.3390x over previous
//
#include <hip/hip_runtime.h>

#define N_NODESC 20000
#define N_EDGESC 640000

typedef _Float16 f16;
typedef __attribute__((ext_vector_type(4))) _Float16 f16x4;
typedef __attribute__((ext_vector_type(8))) _Float16 f16x8;
typedef __attribute__((ext_vector_type(4))) float f32x4;

__device__ __forceinline__ f32x4 mfma16(f16x8 a, f16x8 b, f32x4 c){
  return __builtin_amdgcn_mfma_f32_16x16x32_f16(a, b, c, 0, 0, 0);
}
__device__ __forceinline__ float sigm(float x){ return 1.f/(1.f+__expf(-x)); }
__device__ __forceinline__ float tanh_(float x){
  x = fminf(fmaxf(x, -15.f), 15.f);
  float e = __expf(-2.f*x);
  return (1.f - e)/(1.f + e);
}
__device__ __forceinline__ void stage16(const void* g, void* l){
  __builtin_amdgcn_global_load_lds((const __attribute__((address_space(1))) unsigned int*)g,
                                   (__attribute__((address_space(3))) unsigned int*)l, 16, 0, 0);
}

// ---------------- CSR construction ----------------
__global__ __launch_bounds__(256) void k_hist(const int* __restrict__ dst, int* __restrict__ cnt){
  int e = blockIdx.x*256 + threadIdx.x;
  if(e < N_EDGESC) atomicAdd(&cnt[dst[e]], 1);
}

__global__ __launch_bounds__(1024) void k_scan(const int* __restrict__ cnt, int* __restrict__ row_ptr,
    float* __restrict__ deg_inv, float* __restrict__ deg_is){
  __shared__ int wsum[16];
  int t = threadIdx.x;
  int base = t*20;
  int loc[20]; int s = 0;
  #pragma unroll
  for(int i=0;i<20;i++){ int idx=base+i; int v = (idx<N_NODESC)? cnt[idx] : 0; loc[i]=s; s+=v; }
  int lane = t&63, wv = t>>6;
  int incl = s;
  #pragma unroll
  for(int off=1; off<64; off<<=1){ int u = __shfl_up(incl, off); if(lane>=off) incl += u; }
  if(lane==63) wsum[wv]=incl;
  __syncthreads();
  int woff=0;
  for(int i=0;i<wv;i++) woff += wsum[i];
  int excl = woff + incl - s;
  #pragma unroll
  for(int i=0;i<20;i++){
    int idx=base+i;
    if(idx<N_NODESC){
      row_ptr[idx] = excl + loc[i];
      float d = (float)(cnt[idx]+1);
      deg_inv[idx] = 1.f/d;
      deg_is[idx]  = rsqrtf(d);
    }
  }
  if(t==1023) row_ptr[N_NODESC] = woff + incl;
}

__global__ __launch_bounds__(256) void k_fill(const int* __restrict__ src, const int* __restrict__ dst,
    const int* __restrict__ row_ptr, int* __restrict__ cursor, const float* __restrict__ deg_is,
    int* __restrict__ colv, float* __restrict__ normv){
  int e = blockIdx.x*256 + threadIdx.x;
  if(e >= N_EDGESC) return;
  int d = dst[e], s = src[e];
  int p = atomicAdd(&cursor[d], 1);
  int idx = row_ptr[d] + p;
  colv[idx] = s;
  normv[idx] = deg_is[s]*deg_is[d];
}

// ---------------- weight packing (f16, MFMA B-fragment order) ----------------
// Bp[((kb*NO + c)*4 + g)*8 + i] = B[k = kb*32 + g*8 + i][c]
__global__ __launch_bounds__(256) void k_pack(const float* __restrict__ w, f16* __restrict__ dstp,
    int K, int NO, int trans){
  int t = blockIdx.x*256 + threadIdx.x;
  if(t >= K*NO) return;
  int i = t&7, g = (t>>3)&3, rest = t>>5;
  int c = rest % NO, kb = rest / NO;
  int k = kb*32 + g*8 + i;
  float v = trans ? w[(size_t)c*K + k] : w[(size_t)k*NO + c];
  dstp[t] = (f16)v;
}

// ---------------- aggregation ----------------
// agg64: f32 input (x_seq / decoder out), writes hi/lo f16 planes
__global__ __launch_bounds__(256) void k_agg64(const float* __restrict__ x,
    const int* __restrict__ row_ptr, const int* __restrict__ colv,
    const float* __restrict__ normv, const float* __restrict__ deg_inv,
    f16* __restrict__ Ohi, f16* __restrict__ Olo){
  int n = (blockIdx.x*256 + threadIdx.x)>>6;
  int c = threadIdx.x&63;
  if(n >= N_NODESC) return;
  float acc = deg_inv[n]*x[(size_t)n*64 + c];
  int e0 = row_ptr[n], e1 = row_ptr[n+1];
  int e = e0;
  for(; e+4<=e1; e+=4){
    int s0=colv[e],s1=colv[e+1],s2=colv[e+2],s3=colv[e+3];
    float w0=normv[e],w1=normv[e+1],w2=normv[e+2],w3=normv[e+3];
    float v0=x[(size_t)s0*64+c], v1=x[(size_t)s1*64+c];
    float v2=x[(size_t)s2*64+c], v3=x[(size_t)s3*64+c];
    acc += w0*v0 + w1*v1 + w2*v2 + w3*v3;
  }
  for(; e<e1; e++) acc += normv[e]*x[(size_t)colv[e]*64+c];
  f16 hi = (f16)acc;
  f16 lo = (f16)(acc - (float)hi);
  Ohi[(size_t)n*64+c]=hi; Olo[(size_t)n*64+c]=lo;
}

// agg256: f16 input (x1), f16x4 gather (512B/row), writes hi/lo planes
__global__ __launch_bounds__(256) void k_agg256(const f16* __restrict__ x1,
    const int* __restrict__ row_ptr, const int* __restrict__ colv,
    const float* __restrict__ normv, const float* __restrict__ deg_inv,
    f16* __restrict__ Ohi, f16* __restrict__ Olo){
  int n = (blockIdx.x*256 + threadIdx.x)>>6;
  int lane = threadIdx.x&63;
  if(n >= N_NODESC) return;
  const f16x4* xv = (const f16x4*)x1;
  f32x4 acc = __builtin_convertvector(xv[(size_t)n*64 + lane], f32x4) * deg_inv[n];
  int e0 = row_ptr[n], e1 = row_ptr[n+1];
  int e = e0;
  for(; e+4<=e1; e+=4){
    int s0=colv[e],s1=colv[e+1],s2=colv[e+2],s3=colv[e+3];
    float w0=normv[e],w1=normv[e+1],w2=normv[e+2],w3=normv[e+3];
    f32x4 v0=__builtin_convertvector(xv[(size_t)s0*64+lane], f32x4);
    f32x4 v1=__builtin_convertvector(xv[(size_t)s1*64+lane], f32x4);
    f32x4 v2=__builtin_convertvector(xv[(size_t)s2*64+lane], f32x4);
    f32x4 v3=__builtin_convertvector(xv[(size_t)s3*64+lane], f32x4);
    acc += v0*w0; acc += v1*w1; acc += v2*w2; acc += v3*w3;
  }
  for(; e<e1; e++) acc += __builtin_convertvector(xv[(size_t)colv[e]*64+lane], f32x4)*normv[e];
  f16x4 hi = __builtin_convertvector(acc, f16x4);
  f32x4 hf = __builtin_convertvector(hi, f32x4);
  f16x4 lo = __builtin_convertvector(acc - hf, f16x4);
  ((f16x4*)Ohi)[(size_t)n*64+lane] = hi;
  ((f16x4*)Olo)[(size_t)n*64+lane] = lo;
}

// ---------------- GCN1 GEMM: K=64, N=256, planes A, f16 single out + relu ----------------
__global__ __launch_bounds__(256) void k_gcn1(const f16* __restrict__ Ahi, const f16* __restrict__ Alo,
    const f16* __restrict__ Bp, const float* __restrict__ bias, f16* __restrict__ C){
  __shared__ f16 sA[2][64][64];              // [plane][row][k] rows 128B, chunk^row&7 swizzle
  const int tid = threadIdx.x, lane = tid&63, w = tid>>6;
  const int m0 = blockIdx.x*64;
  const f16* planes[2] = {Ahi, Alo};
  // stage whole K=64: per plane 2 issues of 256x16B
  #pragma unroll
  for(int p=0;p<2;p++){
    #pragma unroll
    for(int j=0;j<2;j++){
      int rloc = j*32 + w*8 + (lane>>3);
      int gr = m0 + rloc; if(gr > N_NODESC-1) gr = N_NODESC-1;
      int chunk = (lane&7) ^ (rloc&7);
      const char* g = (const char*)planes[p] + (size_t)gr*128 + chunk*16;
      char* l = (char*)&sA[p][j*32 + w*8][0] + (lane&7)*16 + ((lane>>3)<<7);
      stage16(g, l);
    }
  }
  __syncthreads();
  f32x4 acc[4][4];
  #pragma unroll
  for(int rt=0;rt<4;rt++)
    #pragma unroll
    for(int ct=0;ct<4;ct++) acc[rt][ct] = (f32x4){0.f,0.f,0.f,0.f};
  const int q = lane>>4;
  #pragma unroll
  for(int kb=0;kb<2;kb++){
    f16x8 bf[4];
    #pragma unroll
    for(int ct=0;ct<4;ct++){
      int c = w*64 + ct*16 + (lane&15);
      bf[ct] = *(const f16x8*)(Bp + (((size_t)kb*256 + c)*4 + q)*8);
    }
    #pragma unroll
    for(int rt=0;rt<4;rt++){
      int r = rt*16 + (lane&15);
      int off = r*64 + (((kb*4+q) ^ (r&7))<<3);
      f16x8 ah = *(const f16x8*)(&sA[0][0][0] + off);
      f16x8 al = *(const f16x8*)(&sA[1][0][0] + off);
      #pragma unroll
      for(int ct=0;ct<4;ct++){
        acc[rt][ct] = mfma16(ah, bf[ct], acc[rt][ct]);
        acc[rt][ct] = mfma16(al, bf[ct], acc[rt][ct]);
      }
    }
  }
  #pragma unroll
  for(int rt=0;rt<4;rt++)
    #pragma unroll
    for(int ct=0;ct<4;ct++){
      int c = w*64 + ct*16 + (lane&15);
      float bv = bias[c];
      #pragma unroll
      for(int j=0;j<4;j++){
        int r = m0 + rt*16 + q*4 + j;
        if(r < N_NODESC) C[(size_t)r*256 + c] = (f16)fmaxf(acc[rt][ct][j] + bv, 0.f);
      }
    }
}

// ---------------- GCN2 GEMM: K=256, N=256, planes A dbuf, hi/lo out + relu (in-place safe) ----
__global__ __launch_bounds__(256,2) void k_gcn2(const f16* __restrict__ Ahi, const f16* __restrict__ Alo,
    const f16* __restrict__ Bp, const float* __restrict__ bias,
    f16* __restrict__ Chi, f16* __restrict__ Clo){
  __shared__ f16 sA[2][2][64][32];           // [buf][plane][row][k], rows 64B, chunk^row&3
  const int tid = threadIdx.x, lane = tid&63, w = tid>>6;
  const int m0 = blockIdx.x*64;
  const int srow = tid>>2;
  int gr = m0 + srow; if(gr > N_NODESC-1) gr = N_NODESC-1;
  const int schunk = (tid&3) ^ (srow&3);
  const size_t sbyte = (size_t)gr*512 + schunk*16;
  const f16* planes[2] = {Ahi, Alo};
  const int q = lane>>4;
  f32x4 acc[4][4];
  #pragma unroll
  for(int rt=0;rt<4;rt++)
    #pragma unroll
    for(int ct=0;ct<4;ct++) acc[rt][ct] = (f32x4){0.f,0.f,0.f,0.f};
  // prologue stage kb=0
  #pragma unroll
  for(int p=0;p<2;p++)
    stage16((const char*)planes[p] + sbyte, (char*)&sA[0][p][w*16][0] + (lane)*16);
  __syncthreads();
  for(int kb=0; kb<8; kb++){
    int b = kb&1;
    if(kb<7){
      #pragma unroll
      for(int p=0;p<2;p++)
        stage16((const char*)planes[p] + sbyte + (kb+1)*64, (char*)&sA[b^1][p][w*16][0] + (lane)*16);
    }
    f16x8 bf[4];
    #pragma unroll
    for(int ct=0;ct<4;ct++){
      int c = w*64 + ct*16 + (lane&15);
      bf[ct] = *(const f16x8*)(Bp + (((size_t)kb*256 + c)*4 + q)*8);
    }
    #pragma unroll
    for(int rt=0;rt<4;rt++){
      int r = rt*16 + (lane&15);
      int off = r*32 + ((q ^ (r&3))<<3);
      f16x8 ah = *(const f16x8*)(&sA[b][0][0][0] + off);
      f16x8 al = *(const f16x8*)(&sA[b][1][0][0] + off);
      #pragma unroll
      for(int ct=0;ct<4;ct++){
        acc[rt][ct] = mfma16(ah, bf[ct], acc[rt][ct]);
        acc[rt][ct] = mfma16(al, bf[ct], acc[rt][ct]);
      }
    }
    __syncthreads();
  }
  #pragma unroll
  for(int rt=0;rt<4;rt++)
    #pragma unroll
    for(int ct=0;ct<4;ct++){
      int c = w*64 + ct*16 + (lane&15);
      float bv = bias[c];
      #pragma unroll
      for(int j=0;j<4;j++){
        int r = m0 + rt*16 + q*4 + j;
        if(r < N_NODESC){
          float v = fmaxf(acc[rt][ct][j] + bv, 0.f);
          f16 hi = (f16)v;
          Chi[(size_t)r*256 + c] = hi;
          Clo[(size_t)r*256 + c] = (f16)(v - (float)hi);
        }
      }
    }
}

// ---------------- fused GRU: planes in, planes out ----------------
__global__ __launch_bounds__(256,2) void k_gru(
    const f16* __restrict__ Xhi, const f16* __restrict__ Xlo,
    const f16* __restrict__ Hhi, const f16* __restrict__ Hlo,
    f16* __restrict__ Nhi, f16* __restrict__ Nlo,
    const f16* __restrict__ Wi, const f16* __restrict__ Wh,
    const float* __restrict__ bih, const float* __restrict__ bhh){
  __shared__ f16 sA[2][4][64][32];           // [buf][plane][row][k]
  const int tid = threadIdx.x, lane = tid&63, w = tid>>6;
  const int m0 = blockIdx.y*64;
  const int cc = blockIdx.x*64 + w*16 + (lane&15);
  const int srow = tid>>2;
  int gr = m0 + srow; if(gr > N_NODESC-1) gr = N_NODESC-1;
  const int schunk = (tid&3) ^ (srow&3);
  const size_t sbyte = (size_t)gr*512 + schunk*16;
  const f16* planes[4] = {Xhi, Xlo, Hhi, Hlo};
  const int q = lane>>4;
  f32x4 acc[6][4];
  #pragma unroll
  for(int m=0;m<6;m++)
    #pragma unroll
    for(int rt=0;rt<4;rt++) acc[m][rt] = (f32x4){0.f,0.f,0.f,0.f};
  #pragma unroll
  for(int p=0;p<4;p++)
    stage16((const char*)planes[p] + sbyte, (char*)&sA[0][p][w*16][0] + lane*16);
  __syncthreads();
  for(int kb=0; kb<8; kb++){
    int b = kb&1;
    if(kb<7){
      #pragma unroll
      for(int p=0;p<4;p++)
        stage16((const char*)planes[p] + sbyte + (kb+1)*64, (char*)&sA[b^1][p][w*16][0] + lane*16);
    }
    f16x8 bi[3], bh[3];
    #pragma unroll
    for(int g3=0;g3<3;g3++){
      size_t o = (((size_t)kb*768 + (cc + g3*256))*4 + q)*8;
      bi[g3] = *(const f16x8*)(Wi + o);
      bh[g3] = *(const f16x8*)(Wh + o);
    }
    #pragma unroll
    for(int rt=0;rt<4;rt++){
      int r = rt*16 + (lane&15);
      int off = r*32 + ((q ^ (r&3))<<3);
      f16x8 axh = *(const f16x8*)(&sA[b][0][0][0] + off);
      f16x8 axl = *(const f16x8*)(&sA[b][1][0][0] + off);
      f16x8 ahh = *(const f16x8*)(&sA[b][2][0][0] + off);
      f16x8 ahl = *(const f16x8*)(&sA[b][3][0][0] + off);
      acc[0][rt] = mfma16(axh, bi[0], acc[0][rt]);
      acc[0][rt] = mfma16(axl, bi[0], acc[0][rt]);
      acc[1][rt] = mfma16(axh, bi[1], acc[1][rt]);
      acc[1][rt] = mfma16(axl, bi[1], acc[1][rt]);
      acc[2][rt] = mfma16(axh, bi[2], acc[2][rt]);
      acc[2][rt] = mfma16(axl, bi[2], acc[2][rt]);
      acc[3][rt] = mfma16(ahh, bh[0], acc[3][rt]);
      acc[3][rt] = mfma16(ahl, bh[0], acc[3][rt]);
      acc[4][rt] = mfma16(ahh, bh[1], acc[4][rt]);
      acc[4][rt] = mfma16(ahl, bh[1], acc[4][rt]);
      acc[5][rt] = mfma16(ahh, bh[2], acc[5][rt]);
      acc[5][rt] = mfma16(ahl, bh[2], acc[5][rt]);
    }
    __syncthreads();
  }
  float bir=bih[cc], biz=bih[cc+256], bin=bih[cc+512];
  float bhr=bhh[cc], bhz=bhh[cc+256], bhn=bhh[cc+512];
  #pragma unroll
  for(int rt=0;rt<4;rt++){
    #pragma unroll
    for(int j=0;j<4;j++){
      int r = m0 + rt*16 + q*4 + j;
      if(r < N_NODESC){
        float ir=acc[0][rt][j], iz=acc[1][rt][j], in_=acc[2][rt][j];
        float hr=acc[3][rt][j], hz=acc[4][rt][j], hn=acc[5][rt][j];
        float rg = sigm(ir+bir + hr+bhr);
        float zg = sigm(iz+biz + hz+bhz);
        float ng = tanh_(in_+bin + rg*(hn+bhn));
        float ho = (float)Hhi[(size_t)r*256 + cc] + (float)Hlo[(size_t)r*256 + cc];
        float v = (1.f-zg)*ng + zg*ho;
        f16 hi = (f16)v;
        Nhi[(size_t)r*256 + cc] = hi;
        Nlo[(size_t)r*256 + cc] = (f16)(v - (float)hi);
      }
    }
  }
}

// ---------------- projection: K=256, N=64, f32 out ----------------
__global__ __launch_bounds__(256,2) void k_proj(const f16* __restrict__ Ahi, const f16* __restrict__ Alo,
    const f16* __restrict__ Bp, const float* __restrict__ bias, float* __restrict__ C){
  __shared__ f16 sA[2][2][64][32];
  const int tid = threadIdx.x, lane = tid&63, w = tid>>6;
  const int m0 = blockIdx.x*64;
  const int cc = w*16 + (lane&15);
  const int srow = tid>>2;
  int gr = m0 + srow; if(gr > N_NODESC-1) gr = N_NODESC-1;
  const int schunk = (tid&3) ^ (srow&3);
  const size_t sbyte = (size_t)gr*512 + schunk*16;
  const f16* planes[2] = {Ahi, Alo};
  const int q = lane>>4;
  f32x4 acc[4];
  #pragma unroll
  for(int rt=0;rt<4;rt++) acc[rt] = (f32x4){0.f,0.f,0.f,0.f};
  #pragma unroll
  for(int p=0;p<2;p++)
    stage16((const char*)planes[p] + sbyte, (char*)&sA[0][p][w*16][0] + lane*16);
  __syncthreads();
  for(int kb=0; kb<8; kb++){
    int b = kb&1;
    if(kb<7){
      #pragma unroll
      for(int p=0;p<2;p++)
        stage16((const char*)planes[p] + sbyte + (kb+1)*64, (char*)&sA[b^1][p][w*16][0] + lane*16);
    }
    f16x8 bf = *(const f16x8*)(Bp + (((size_t)kb*64 + cc)*4 + q)*8);
    #pragma unroll
    for(int rt=0;rt<4;rt++){
      int r = rt*16 + (lane&15);
      int off = r*32 + ((q ^ (r&3))<<3);
      f16x8 ah = *(const f16x8*)(&sA[b][0][0][0] + off);
      f16x8 al = *(const f16x8*)(&sA[b][1][0][0] + off);
      acc[rt] = mfma16(ah, bf, acc[rt]);
      acc[rt] = mfma16(al, bf, acc[rt]);
    }
    __syncthreads();
  }
  #pragma unroll
  for(int rt=0;rt<4;rt++){
    float bv = bias[cc];
    #pragma unroll
    for(int j=0;j<4;j++){
      int r = m0 + rt*16 + q*4 + j;
      if(r < N_NODESC) C[(size_t)r*64 + cc] = acc[rt][j] + bv;
    }
  }
}

// ---------------- launcher ----------------
extern "C" void kernel_launch(void* const* d_in, const int* in_sizes, int n_in,
                              void* d_out, int out_size, void* d_ws, size_t ws_size,
                              hipStream_t stream){
  const float* x_seq  = (const float*)d_in[0];
  const int*   srcp   = (const int*)  d_in[1];
  const int*   dstp   = (const int*)  d_in[2];
  const float* gcn1_w = (const float*)d_in[3];
  const float* gcn1_b = (const float*)d_in[4];
  const float* gcn2_w = (const float*)d_in[5];
  const float* gcn2_b = (const float*)d_in[6];
  const float* proj_w = (const float*)d_in[7];
  const float* proj_b = (const float*)d_in[8];
  const float* wih[3] = {(const float*)d_in[9],  (const float*)d_in[13], (const float*)d_in[17]};
  const float* whh[3] = {(const float*)d_in[10], (const float*)d_in[14], (const float*)d_in[18]};
  const float* bih[3] = {(const float*)d_in[11], (const float*)d_in[15], (const float*)d_in[19]};
  const float* bhh[3] = {(const float*)d_in[12], (const float*)d_in[16], (const float*)d_in[20]};
  float* out = (float*)d_out;

  const size_t NP = (size_t)N_NODESC*256;
  char* p = (char*)d_ws;
  auto alloc = [&](size_t bytes)->char*{ char* r = p; p += (bytes + 255) & ~(size_t)255; return r; };
  int*   deg_cnt = (int*)  alloc((size_t)2*N_NODESC*4);
  int*   cursor  = deg_cnt + N_NODESC;
  int*   row_ptr = (int*)  alloc((size_t)(N_NODESC+1)*4);
  float* deg_inv = (float*)alloc((size_t)N_NODESC*4);
  float* deg_is  = (float*)alloc((size_t)N_NODESC*4);
  int*   colv    = (int*)  alloc((size_t)N_EDGESC*4);
  float* normv   = (float*)alloc((size_t)N_EDGESC*4);
  f16* z64h = (f16*)alloc((size_t)N_NODESC*64*2);
  f16* z64l = (f16*)alloc((size_t)N_NODESC*64*2);
  f16* x1   = (f16*)alloc(NP*2);
  f16* xah  = (f16*)alloc(NP*2);
  f16* xal  = (f16*)alloc(NP*2);
  f16* hbuf = (f16*)alloc((size_t)2*3*2*NP*2);   // [slot][gru][plane]
  f16* pk_gcn1 = (f16*)alloc((size_t)64*256*2);
  f16* pk_gcn2 = (f16*)alloc((size_t)256*256*2);
  f16* pk_proj = (f16*)alloc((size_t)256*64*2);
  f16* pk_wi[3]; f16* pk_wh[3];
  for(int i=0;i<3;i++){ pk_wi[i]=(f16*)alloc((size_t)256*768*2); pk_wh[i]=(f16*)alloc((size_t)256*768*2); }

  hipMemsetAsync(deg_cnt, 0, (size_t)2*N_NODESC*4, stream);
  hipMemsetAsync(hbuf,    0, (size_t)3*2*NP*2, stream);   // slot 0 planes = h0

  k_hist<<<2500,256,0,stream>>>(dstp, deg_cnt);
  k_scan<<<1,1024,0,stream>>>(deg_cnt, row_ptr, deg_inv, deg_is);
  k_fill<<<2500,256,0,stream>>>(srcp, dstp, row_ptr, cursor, deg_is, colv, normv);

  k_pack<<<64, 256,0,stream>>>(gcn1_w, pk_gcn1, 64, 256, 0);
  k_pack<<<256,256,0,stream>>>(gcn2_w, pk_gcn2, 256,256, 0);
  k_pack<<<64, 256,0,stream>>>(proj_w, pk_proj, 256, 64, 0);
  for(int i=0;i<3;i++){
    k_pack<<<768,256,0,stream>>>(wih[i], pk_wi[i], 256, 768, 1);
    k_pack<<<768,256,0,stream>>>(whh[i], pk_wh[i], 256, 768, 1);
  }

  auto Hh = [&](int slot, int g)->f16*{ return hbuf + ((size_t)(slot*3+g)*2 + 0)*NP; };
  auto Hl = [&](int slot, int g)->f16*{ return hbuf + ((size_t)(slot*3+g)*2 + 1)*NP; };

  for(int s=0; s<18; s++){
    const float* xt;
    if(s < 12)       xt = x_seq + (size_t)s*N_NODESC*64;
    else if(s == 12) xt = x_seq + (size_t)11*N_NODESC*64;
    else             xt = out   + (size_t)(s-13)*N_NODESC*64;
    int cur = s&1, nxt = cur^1;

    k_agg64 <<<5000,256,0,stream>>>(xt, row_ptr, colv, normv, deg_inv, z64h, z64l);
    k_gcn1  <<<313, 256,0,stream>>>(z64h, z64l, pk_gcn1, gcn1_b, x1);
    k_agg256<<<5000,256,0,stream>>>(x1, row_ptr, colv, normv, deg_inv, xah, xal);
    k_gcn2  <<<313, 256,0,stream>>>(xah, xal, pk_gcn2, gcn2_b, xah, xal);

    k_gru<<<dim3(4,313),256,0,stream>>>(xah, xal,           Hh(cur,0),Hl(cur,0), Hh(nxt,0),Hl(nxt,0), pk_wi[0], pk_wh[0], bih[0], bhh[0]);
    k_gru<<<dim3(4,313),256,0,stream>>>(Hh(nxt,0),Hl(nxt,0),Hh(cur,1),Hl(cur,1), Hh(nxt,1),Hl(nxt,1), pk_wi[1], pk_wh[1], bih[1], bhh[1]);
    k_gru<<<dim3(4,313),256,0,stream>>>(Hh(nxt,1),Hl(nxt,1),Hh(cur,2),Hl(cur,2), Hh(nxt,2),Hl(nxt,2), pk_wi[2], pk_wh[2], bih[2], bhh[2]);

    if(s >= 12)
      k_proj<<<313,256,0,stream>>>(Hh(nxt,2), Hl(nxt,2), pk_proj, proj_b, out + (size_t)(s-12)*N_NODESC*64);
  }
}